// Round 1
// baseline (5013.198 us; speedup 1.0000x reference)
//
#include <hip/hip_runtime.h>
#include <math.h>

#define KSEL 153
#define NT 512
#define DDIM 512
#define BATCH 256
#define MTOT (BATCH * KSEL)   // 39168

// ---------------------------------------------------------------------------
// Stage 1: per-batch prep — eos, lengths, masked attention row, exact top-k
// via full bitonic sort of (ordered_float_value, 511-index) keys (desc).
// Matches jax.lax.top_k semantics: value desc, lower index wins ties.
// ---------------------------------------------------------------------------
__global__ __launch_bounds__(512) void prep_kernel(
    const int* __restrict__ text, const float* __restrict__ atten,
    int* __restrict__ idx, int* __restrict__ lens) {
  int b = blockIdx.x;
  int t = threadIdx.x;  // 0..511
  __shared__ int red[512];
  __shared__ int eos_s;
  __shared__ int cnt_s;
  __shared__ unsigned long long keys[512];

  int ti = text[b * NT + t];
  red[t] = ti;
  if (t == 0) { eos_s = 0x7fffffff; cnt_s = 0; }
  __syncthreads();
  for (int s = 256; s > 0; s >>= 1) {
    if (t < s) red[t] = max(red[t], red[t + s]);
    __syncthreads();
  }
  int mxv = red[0];
  if (ti == mxv) atomicMin(&eos_s, t);  // argmax = first index of max
  unsigned long long bal = __ballot(ti != 0);
  if ((t & 63) == 0) atomicAdd(&cnt_s, __popcll(bal));
  __syncthreads();
  int eos = eos_s;

  // row = atten[b, eos, :]; row[eos]=-1; row[0]=-1; row *= mask
  float v;
  if (ti == 0) v = 0.0f;                       // pad -> exactly +0.0
  else if (t == 0 || t == eos) v = -1.0f;
  else v = atten[((size_t)b * NT + eos) * NT + t];
  unsigned int fb = __float_as_uint(v);
  unsigned int ordv = (v >= 0.0f) ? (fb | 0x80000000u) : ~fb;  // monotone map
  keys[t] = ((unsigned long long)ordv << 32) | (unsigned int)(511 - t);
  __syncthreads();

  // bitonic sort, descending
  for (int k2 = 2; k2 <= 512; k2 <<= 1) {
    for (int j = k2 >> 1; j > 0; j >>= 1) {
      int ixj = t ^ j;
      if (ixj > t) {
        unsigned long long a = keys[t], bb = keys[ixj];
        bool up = ((t & k2) == 0);
        bool sw = up ? (a < bb) : (a > bb);
        if (sw) { keys[t] = bb; keys[ixj] = a; }
      }
      __syncthreads();
    }
  }
  if (t < KSEL) idx[b * KSEL + t] = 511 - (int)(keys[t] & 0xffffffffu);
  if (t == 0) {
    int L = cnt_s - 2;           // lengths
    L = min(L, KSEL); L = max(L, 1);
    lens[b] = L;
  }
}

// ---------------------------------------------------------------------------
// Stage 2: gather selected feature rows, L2-normalize, LayerNorm -> q
// One block (256 thr) per token row; each thread owns cols t and t+256.
// ---------------------------------------------------------------------------
__global__ __launch_bounds__(256) void gather_ln_kernel(
    const float* __restrict__ features, const int* __restrict__ idx,
    const float* __restrict__ lnw, const float* __restrict__ lnb,
    float* __restrict__ tok, float* __restrict__ q) {
  int m = blockIdx.x;           // 0..MTOT-1
  int b = m / KSEL;
  int t = threadIdx.x;
  int src = idx[m];
  const float* f = features + ((size_t)b * NT + src) * DDIM;
  float v0 = f[t], v1 = f[t + 256];
  float s1 = v0 + v1, s2 = v0 * v0 + v1 * v1;
  for (int o = 32; o > 0; o >>= 1) {
    s1 += __shfl_xor(s1, o);
    s2 += __shfl_xor(s2, o);
  }
  __shared__ float w1[4], w2[4];
  int wv = t >> 6;
  if ((t & 63) == 0) { w1[wv] = s1; w2[wv] = s2; }
  __syncthreads();
  s1 = w1[0] + w1[1] + w1[2] + w1[3];
  s2 = w2[0] + w2[1] + w2[2] + w2[3];
  float dn = sqrtf(s2) + 1e-6f;             // L2 norm denom
  float t0 = v0 / dn, t1 = v1 / dn;
  float mean = s1 / dn * (1.0f / DDIM);
  float ex2 = s2 / (dn * dn) * (1.0f / DDIM);
  float var = ex2 - mean * mean;
  float is = rsqrtf(var + 1e-5f);
  size_t rowo = (size_t)m * DDIM;
  tok[rowo + t] = t0;
  tok[rowo + t + 256] = t1;
  q[rowo + t] = (t0 - mean) * is * lnw[t] + lnb[t];
  q[rowo + t + 256] = (t1 - mean) * is * lnw[t + 256] + lnb[t + 256];
}

// ---------------------------------------------------------------------------
// Generic tiled fp32 GEMM: C[M,N] = epilogue(A[M,K] @ W[N,K]^T + bias)
// BM=BN=64, BK=16, 256 threads, 4x4 per thread.
// MODE 0: none   1: exact gelu   2: out = EXTRA + sigmoid(*gptr)*x
// MODE 3: out = x + EXTRA
// M,N multiples of 64; K multiple of 16 (true for all calls here).
// ---------------------------------------------------------------------------
template <int MODE>
__global__ __launch_bounds__(256) void gemm_kernel(
    const float* __restrict__ A, const float* __restrict__ W,
    const float* __restrict__ bias, float* __restrict__ C,
    const float* __restrict__ EXTRA, const float* __restrict__ gptr,
    int M, int N, int K) {
  __shared__ float As[16][64];
  __shared__ float Ws[16][64];
  int t = threadIdx.x;
  int tx = t & 15, ty = t >> 4;
  int m0 = blockIdx.y * 64, n0 = blockIdx.x * 64;
  int lr = t >> 2;
  int lc = (t & 3) << 2;
  const float* Ap = A + (size_t)(m0 + lr) * K + lc;
  const float* Wp = W + (size_t)(n0 + lr) * K + lc;
  float c[4][4];
#pragma unroll
  for (int i = 0; i < 4; ++i)
#pragma unroll
    for (int j = 0; j < 4; ++j) c[i][j] = 0.0f;

  for (int k0 = 0; k0 < K; k0 += 16) {
    float4 av = *(const float4*)(Ap + k0);
    float4 wv = *(const float4*)(Wp + k0);
    __syncthreads();
    As[lc + 0][lr] = av.x; As[lc + 1][lr] = av.y;
    As[lc + 2][lr] = av.z; As[lc + 3][lr] = av.w;
    Ws[lc + 0][lr] = wv.x; Ws[lc + 1][lr] = wv.y;
    Ws[lc + 2][lr] = wv.z; Ws[lc + 3][lr] = wv.w;
    __syncthreads();
#pragma unroll
    for (int kk = 0; kk < 16; ++kk) {
      float4 a4 = *(const float4*)&As[kk][ty * 4];
      float4 b4 = *(const float4*)&Ws[kk][tx * 4];
      float aa[4] = {a4.x, a4.y, a4.z, a4.w};
      float bb[4] = {b4.x, b4.y, b4.z, b4.w};
#pragma unroll
      for (int i = 0; i < 4; ++i)
#pragma unroll
        for (int j = 0; j < 4; ++j) c[i][j] += aa[i] * bb[j];
    }
  }

  float sg = 0.0f;
  if (MODE == 2) sg = 1.0f / (1.0f + expf(-gptr[0]));
#pragma unroll
  for (int i = 0; i < 4; ++i) {
    int m = m0 + ty * 4 + i;
#pragma unroll
    for (int j = 0; j < 4; ++j) {
      int n = n0 + tx * 4 + j;
      float x = c[i][j] + bias[n];
      if (MODE == 1) x = 0.5f * x * (1.0f + erff(x * 0.70710678118654752f));
      if (MODE == 2) x = EXTRA[(size_t)m * N + n] + sg * x;
      if (MODE == 3) x = x + EXTRA[(size_t)m * N + n];
      c[i][j] = x;
    }
    float4 o4 = {c[i][0], c[i][1], c[i][2], c[i][3]};
    *(float4*)(C + (size_t)m * N + n0 + tx * 4) = o4;
  }
}

// ---------------------------------------------------------------------------
// Stage 4: self-attention, one block (256 thr) per (batch, head).
// qkv row layout: [0:512) q | [512:1024) k | [1024:1536) v ; head h = cols h*64..
// K head-slab staged in LDS; 16-row query tiles; softmax via 16-lane shuffles.
// ---------------------------------------------------------------------------
__global__ __launch_bounds__(256) void attn_kernel(
    const float* __restrict__ qkv, float* __restrict__ sa) {
  int bh = blockIdx.x;
  int b = bh >> 3;
  int h = bh & 7;
  __shared__ float Ks[KSEL][68];   // +4 pad: kills 16-way bank conflicts
  __shared__ float Qs[16][68];
  __shared__ float Ss[16][156];
  __shared__ float rinv[16];
  int t = threadIdx.x;
  const float* base = qkv + (size_t)b * KSEL * 1536;

  for (int e = t; e < KSEL * 64; e += 256) {
    int j = e >> 6, d = e & 63;
    Ks[j][d] = base[(size_t)j * 1536 + 512 + h * 64 + d];
  }
  __syncthreads();

  for (int i0 = 0; i0 < KSEL; i0 += 16) {
    int rows = min(16, KSEL - i0);
    for (int e = t; e < rows * 64; e += 256) {
      int i = e >> 6, d = e & 63;
      Qs[i][d] = base[(size_t)(i0 + i) * 1536 + h * 64 + d];
    }
    __syncthreads();

    int i = t >> 4, jl = t & 15;
    if (i < rows) {
      for (int j = jl; j < KSEL; j += 16) {
        float acc = 0.0f;
#pragma unroll
        for (int d = 0; d < 64; d += 4) {
          float4 q4 = *(const float4*)&Qs[i][d];
          float4 k4 = *(const float4*)&Ks[j][d];
          acc += q4.x * k4.x + q4.y * k4.y + q4.z * k4.z + q4.w * k4.w;
        }
        Ss[i][j] = acc * 0.125f;   // 1/sqrt(64)
      }
    }
    __syncthreads();

    if (i < rows) {
      float mx = -3.0e38f;
      for (int j = jl; j < KSEL; j += 16) mx = fmaxf(mx, Ss[i][j]);
      for (int o = 8; o > 0; o >>= 1) mx = fmaxf(mx, __shfl_xor(mx, o));
      float sm = 0.0f;
      for (int j = jl; j < KSEL; j += 16) {
        float e = expf(Ss[i][j] - mx);
        Ss[i][j] = e;
        sm += e;
      }
      for (int o = 8; o > 0; o >>= 1) sm += __shfl_xor(sm, o);
      if (jl == 0) rinv[i] = 1.0f / sm;
    }
    __syncthreads();

    {
      int ii = t >> 4, d0 = (t & 15) * 4;
      if (ii < rows) {
        float ax = 0.f, ay = 0.f, az = 0.f, aw = 0.f;
        for (int j = 0; j < KSEL; ++j) {
          float p = Ss[ii][j];
          float4 v4 = *(const float4*)&base[(size_t)j * 1536 + 1024 + h * 64 + d0];
          ax += p * v4.x; ay += p * v4.y; az += p * v4.z; aw += p * v4.w;
        }
        float r = rinv[ii];
        float4 o4 = {ax * r, ay * r, az * r, aw * r};
        *(float4*)&sa[(size_t)(b * KSEL + i0 + ii) * DDIM + h * 64 + d0] = o4;
      }
    }
    __syncthreads();
  }
}

// ---------------------------------------------------------------------------
// BatchNorm (train-mode stats over all MTOT rows, 512 channels)
// ---------------------------------------------------------------------------
__global__ __launch_bounds__(256) void bn_stats_kernel(
    const float* __restrict__ h, float* __restrict__ sum, float* __restrict__ ssq) {
  int blk = blockIdx.x;   // 306 blocks * 128 rows
  int t = threadIdx.x;
  float a0 = 0.f, a1 = 0.f, q0 = 0.f, q1 = 0.f;
  for (int r = 0; r < 128; ++r) {
    const float* row = h + ((size_t)blk * 128 + r) * 512;
    float v0 = row[t], v1 = row[t + 256];
    a0 += v0; q0 += v0 * v0;
    a1 += v1; q1 += v1 * v1;
  }
  atomicAdd(&sum[t], a0);       atomicAdd(&ssq[t], q0);
  atomicAdd(&sum[t + 256], a1); atomicAdd(&ssq[t + 256], q1);
}

__global__ void bn_finalize_kernel(const float* __restrict__ sum,
                                   const float* __restrict__ ssq,
                                   float* __restrict__ mu, float* __restrict__ istd) {
  int c = blockIdx.x * 256 + threadIdx.x;
  if (c < 512) {
    float m = sum[c] * (1.0f / MTOT);
    float v = ssq[c] * (1.0f / MTOT) - m * m;
    mu[c] = m;
    istd[c] = rsqrtf(v + 1e-5f);
  }
}

__global__ __launch_bounds__(256) void bn_apply_kernel(
    float* __restrict__ h, const float* __restrict__ mu, const float* __restrict__ istd,
    const float* __restrict__ w, const float* __restrict__ b) {
  int i4 = blockIdx.x * 256 + threadIdx.x;   // one float4 each
  int c0 = (i4 * 4) & 511;
  float4 v = *(float4*)&h[(size_t)i4 * 4];
  v.x = fmaxf((v.x - mu[c0 + 0]) * istd[c0 + 0] * w[c0 + 0] + b[c0 + 0], 0.f);
  v.y = fmaxf((v.y - mu[c0 + 1]) * istd[c0 + 1] * w[c0 + 1] + b[c0 + 1], 0.f);
  v.z = fmaxf((v.z - mu[c0 + 2]) * istd[c0 + 2] * w[c0 + 2] + b[c0 + 2], 0.f);
  v.w = fmaxf((v.w - mu[c0 + 3]) * istd[c0 + 3] * w[c0 + 3] + b[c0 + 3], 0.f);
  *(float4*)&h[(size_t)i4 * 4] = v;
}

// ---------------------------------------------------------------------------
// Stage 8: variable-length max pool over first lens[b] ranked tokens
// ---------------------------------------------------------------------------
__global__ __launch_bounds__(256) void pool_kernel(
    const float* __restrict__ feat, const int* __restrict__ lens,
    float* __restrict__ out) {
  int b = blockIdx.x;
  int t = threadIdx.x;
  int L = lens[b];
  for (int e = t; e < 1024; e += 256) {
    const float* p = feat + (size_t)b * KSEL * 1024 + e;
    float mx = -3.0e38f;
    for (int i = 0; i < L; ++i) mx = fmaxf(mx, p[(size_t)i * 1024]);
    out[(size_t)b * 1024 + e] = mx;
  }
}

// ---------------------------------------------------------------------------
extern "C" void kernel_launch(void* const* d_in, const int* in_sizes, int n_in,
                              void* d_out, int out_size, void* d_ws, size_t ws_size,
                              hipStream_t stream) {
  const float* features = (const float*)d_in[0];
  const int*   text     = (const int*)d_in[1];
  const float* atten    = (const float*)d_in[2];
  const float* ln_q_w   = (const float*)d_in[3];
  const float* ln_q_b   = (const float*)d_in[4];
  const float* sa_in_w  = (const float*)d_in[5];
  const float* sa_in_b  = (const float*)d_in[6];
  const float* sa_out_w = (const float*)d_in[7];
  const float* sa_out_b = (const float*)d_in[8];
  const float* ref_w1   = (const float*)d_in[9];
  const float* ref_b1   = (const float*)d_in[10];
  const float* ref_w2   = (const float*)d_in[11];
  const float* ref_b2   = (const float*)d_in[12];
  const float* gptr     = (const float*)d_in[13];
  const float* lin_w    = (const float*)d_in[14];
  const float* lin_b    = (const float*)d_in[15];
  const float* mlp_w1   = (const float*)d_in[16];
  const float* mlp_b1   = (const float*)d_in[17];
  const float* bn_w     = (const float*)d_in[18];
  const float* bn_b     = (const float*)d_in[19];
  const float* mlp_w2   = (const float*)d_in[20];
  const float* mlp_b2   = (const float*)d_in[21];
  float* out = (float*)d_out;

  char* wsb = (char*)d_ws;
  int*   idxp  = (int*)(wsb + 0);                 // 39168*4
  int*   lensp = (int*)(wsb + 156672);            // 256*4
  float* sump  = (float*)(wsb + 157696);          // 512*4
  float* ssqp  = (float*)(wsb + 159744);          // 512*4
  float* mup   = (float*)(wsb + 161792);          // 512*4
  float* istdp = (float*)(wsb + 163840);          // 512*4
  float* tokp  = (float*)(wsb + 262144);          // M*512 f32 = 80216064 B
  float* Areg  = (float*)(wsb + 80478208);        // M*1536 f32 = 240648192 B
  float* Breg  = (float*)(wsb + 321126400);       // M*1024 f32 = 160432128 B
  // total ws needed: 481558528 B

  // sub-views (buffer reuse)
  float* Qbuf  = Breg;            // [M,512] LN output
  float* QKV   = Areg;            // [M,1536]
  float* SA    = Breg;            // [M,512] (overwrites Q after qkv consumed)
  float* S2    = Areg;            // [M,512] sa_out result (qkv dead)
  float* Hbuf  = Breg;            // [M,1024] gelu hidden (sa dead)
  float* CAP   = Areg;            // [M,1024] cap, then feat in-place
  float* H1    = Breg;            // [M,512] mlp1 pre-BN (Hbuf dead)

  hipMemsetAsync(wsb + 157696, 0, 4096, stream);  // zero sum+ssq

  prep_kernel<<<BATCH, 512, 0, stream>>>(text, atten, idxp, lensp);
  gather_ln_kernel<<<MTOT, 256, 0, stream>>>(features, idxp, ln_q_w, ln_q_b,
                                             tokp, Qbuf);
  // qkv = LN(tok) @ sa_in_w^T + b     [M,1536]
  gemm_kernel<0><<<dim3(1536 / 64, MTOT / 64), 256, 0, stream>>>(
      Qbuf, sa_in_w, sa_in_b, QKV, nullptr, nullptr, MTOT, 1536, 512);
  // self-attention -> SA [M,512]
  attn_kernel<<<BATCH * 8, 256, 0, stream>>>(QKV, SA);
  // S2 = SA @ sa_out_w^T + b          [M,512]
  gemm_kernel<0><<<dim3(512 / 64, MTOT / 64), 256, 0, stream>>>(
      SA, sa_out_w, sa_out_b, S2, nullptr, nullptr, MTOT, 512, 512);
  // H = gelu(S2 @ ref_w1^T + b)       [M,1024]
  gemm_kernel<1><<<dim3(1024 / 64, MTOT / 64), 256, 0, stream>>>(
      S2, ref_w1, ref_b1, Hbuf, nullptr, nullptr, MTOT, 1024, 512);
  // tok = tok + sigmoid(g) * (H @ ref_w2^T + b)   (in place on tok)
  gemm_kernel<2><<<dim3(512 / 64, MTOT / 64), 256, 0, stream>>>(
      Hbuf, ref_w2, ref_b2, tokp, tokp, gptr, MTOT, 512, 1024);
  // cap = tok @ lin_w^T + b           [M,1024]
  gemm_kernel<0><<<dim3(1024 / 64, MTOT / 64), 256, 0, stream>>>(
      tokp, lin_w, lin_b, CAP, nullptr, nullptr, MTOT, 1024, 512);
  // h = tok @ mlp_w1^T + b            [M,512]
  gemm_kernel<0><<<dim3(512 / 64, MTOT / 64), 256, 0, stream>>>(
      tokp, mlp_w1, mlp_b1, H1, nullptr, nullptr, MTOT, 512, 512);
  // BN train-mode stats + apply + relu (in place on H1)
  bn_stats_kernel<<<MTOT / 128, 256, 0, stream>>>(H1, sump, ssqp);
  bn_finalize_kernel<<<2, 256, 0, stream>>>(sump, ssqp, mup, istdp);
  bn_apply_kernel<<<(MTOT * 512 / 4) / 256, 256, 0, stream>>>(H1, mup, istdp,
                                                              bn_w, bn_b);
  // feat = relu_bn(h) @ mlp_w2^T + b + cap   (in place on CAP)
  gemm_kernel<3><<<dim3(1024 / 64, MTOT / 64), 256, 0, stream>>>(
      H1, mlp_w2, mlp_b2, CAP, CAP, nullptr, MTOT, 1024, 512);
  // masked max pool
  pool_kernel<<<BATCH, 256, 0, stream>>>(CAP, lensp, out);
}

// Round 2
// 1811.454 us; speedup vs baseline: 2.7675x; 2.7675x over previous
//
#include <hip/hip_runtime.h>
#include <math.h>

#define KSEL 153
#define NT 512
#define DDIM 512
#define BATCH 256
#define MTOT (BATCH * KSEL)   // 39168

typedef unsigned short ushort_t;
typedef short bf16x8 __attribute__((ext_vector_type(8)));
typedef float f32x4 __attribute__((ext_vector_type(4)));

__device__ __forceinline__ ushort_t f2bf(float f) {
  unsigned u = __float_as_uint(f);
  u += 0x7fffu + ((u >> 16) & 1u);       // RNE
  return (ushort_t)(u >> 16);
}
__device__ __forceinline__ float bf2f(ushort_t s) {
  return __uint_as_float(((unsigned)s) << 16);
}
__device__ __forceinline__ void gload16(const void* g, void* l) {
  __builtin_amdgcn_global_load_lds(
      (const __attribute__((address_space(1))) unsigned int*)g,
      (__attribute__((address_space(3))) unsigned int*)l, 16, 0, 0);
}

// ---------------------------------------------------------------------------
// Stage 1: per-batch prep — eos, lengths, exact top-k via bitonic sort.
// ---------------------------------------------------------------------------
__global__ __launch_bounds__(512) void prep_kernel(
    const int* __restrict__ text, const float* __restrict__ atten,
    int* __restrict__ idx, int* __restrict__ lens) {
  int b = blockIdx.x;
  int t = threadIdx.x;  // 0..511
  __shared__ int red[512];
  __shared__ int eos_s;
  __shared__ int cnt_s;
  __shared__ unsigned long long keys[512];

  int ti = text[b * NT + t];
  red[t] = ti;
  if (t == 0) { eos_s = 0x7fffffff; cnt_s = 0; }
  __syncthreads();
  for (int s = 256; s > 0; s >>= 1) {
    if (t < s) red[t] = max(red[t], red[t + s]);
    __syncthreads();
  }
  int mxv = red[0];
  if (ti == mxv) atomicMin(&eos_s, t);
  unsigned long long bal = __ballot(ti != 0);
  if ((t & 63) == 0) atomicAdd(&cnt_s, __popcll(bal));
  __syncthreads();
  int eos = eos_s;

  float v;
  if (ti == 0) v = 0.0f;
  else if (t == 0 || t == eos) v = -1.0f;
  else v = atten[((size_t)b * NT + eos) * NT + t];
  unsigned int fb = __float_as_uint(v);
  unsigned int ordv = (v >= 0.0f) ? (fb | 0x80000000u) : ~fb;
  keys[t] = ((unsigned long long)ordv << 32) | (unsigned int)(511 - t);
  __syncthreads();

  for (int k2 = 2; k2 <= 512; k2 <<= 1) {
    for (int j = k2 >> 1; j > 0; j >>= 1) {
      int ixj = t ^ j;
      if (ixj > t) {
        unsigned long long a = keys[t], bb = keys[ixj];
        bool up = ((t & k2) == 0);
        bool sw = up ? (a < bb) : (a > bb);
        if (sw) { keys[t] = bb; keys[ixj] = a; }
      }
      __syncthreads();
    }
  }
  if (t < KSEL) idx[b * KSEL + t] = 511 - (int)(keys[t] & 0xffffffffu);
  if (t == 0) {
    int L = cnt_s - 2;
    L = min(L, KSEL); L = max(L, 1);
    lens[b] = L;
  }
}

// ---------------------------------------------------------------------------
// Stage 2: gather + L2-normalize + LayerNorm; writes tok(bf16) and q(bf16).
// ---------------------------------------------------------------------------
__global__ __launch_bounds__(256) void gather_ln_kernel(
    const float* __restrict__ features, const int* __restrict__ idx,
    const float* __restrict__ lnw, const float* __restrict__ lnb,
    ushort_t* __restrict__ tokb, ushort_t* __restrict__ qb) {
  int m = blockIdx.x;
  int b = m / KSEL;
  int t = threadIdx.x;
  int src = idx[m];
  const float* f = features + ((size_t)b * NT + src) * DDIM;
  float v0 = f[t], v1 = f[t + 256];
  float s1 = v0 + v1, s2 = v0 * v0 + v1 * v1;
  for (int o = 32; o > 0; o >>= 1) {
    s1 += __shfl_xor(s1, o);
    s2 += __shfl_xor(s2, o);
  }
  __shared__ float w1[4], w2[4];
  int wv = t >> 6;
  if ((t & 63) == 0) { w1[wv] = s1; w2[wv] = s2; }
  __syncthreads();
  s1 = w1[0] + w1[1] + w1[2] + w1[3];
  s2 = w2[0] + w2[1] + w2[2] + w2[3];
  float dn = sqrtf(s2) + 1e-6f;
  float t0 = v0 / dn, t1 = v1 / dn;
  float mean = s1 / dn * (1.0f / DDIM);
  float ex2 = s2 / (dn * dn) * (1.0f / DDIM);
  float var = ex2 - mean * mean;
  float is = rsqrtf(var + 1e-5f);
  size_t rowo = (size_t)m * DDIM;
  tokb[rowo + t] = f2bf(t0);
  tokb[rowo + t + 256] = f2bf(t1);
  qb[rowo + t] = f2bf((t0 - mean) * is * lnw[t] + lnb[t]);
  qb[rowo + t + 256] = f2bf((t1 - mean) * is * lnw[t + 256] + lnb[t + 256]);
}

// ---------------------------------------------------------------------------
// Weight fp32 -> bf16 conversion (all 7 matrices, one kernel).
// ---------------------------------------------------------------------------
struct WConvArgs {
  const float* src[7];
  int e[8];   // cumulative element offsets
};
__global__ __launch_bounds__(256) void wconv_kernel(WConvArgs a, ushort_t* dst) {
  int gid = blockIdx.x * 256 + threadIdx.x;
  int el = gid * 4;
  if (el >= a.e[7]) return;
  int r = 0;
#pragma unroll
  for (int i = 1; i < 7; ++i) r += (el >= a.e[i]) ? 1 : 0;
  const float* s = a.src[r] + (el - a.e[r]);
  float4 v = *(const float4*)s;
  ushort4 o;
  o.x = f2bf(v.x); o.y = f2bf(v.y); o.z = f2bf(v.z); o.w = f2bf(v.w);
  *(ushort4*)(dst + el) = o;
}

// ---------------------------------------------------------------------------
// MFMA bf16 GEMM: C[M,N] = epi(A[M,K] @ W[N,K]^T + bias)
// 128x128 tile, BK=32, 256 thr (4 waves x 64x64), global_load_lds staging
// with XOR-swizzled global source so LDS dest stays lane-contiguous.
// MODE 0: bias  1: +exact gelu  2: out = bf(EXTRA) + sigmoid(*gptr)*x
// MODE 3: out = x + bf(EXTRA).  OUTBF: write bf16 else fp32.
// M%128==0, N%128==0, K%32==0.
// ---------------------------------------------------------------------------
template <int MODE, int OUTBF>
__global__ __launch_bounds__(256) void mfma_gemm(
    const ushort_t* __restrict__ A, const ushort_t* __restrict__ W,
    const float* __restrict__ bias, void* __restrict__ Cout,
    const ushort_t* __restrict__ EXTRA, const float* __restrict__ gptr,
    int M, int N, int K) {
  __shared__ ushort_t As[128 * 32];
  __shared__ ushort_t Bs[128 * 32];
  int t = threadIdx.x;
  int lane = t & 63;
  int wv = t >> 6;
  int m0 = blockIdx.y * 128, n0 = blockIdx.x * 128;
  int wm = (wv >> 1) * 64, wn = (wv & 1) * 64;
  int quad = lane >> 4, lr = lane & 15;

  f32x4 acc[4][4];
#pragma unroll
  for (int i = 0; i < 4; ++i)
#pragma unroll
    for (int j = 0; j < 4; ++j) acc[i][j] = (f32x4){0.f, 0.f, 0.f, 0.f};

  // staging: 512 16B-chunks per tile, 2 per thread. chunk f -> row=f>>2, slot=f&3
  // LDS slot s of row holds global colgroup cg = s ^ (row&3).
  int f0 = t, f1 = t + 256;
  int rA0 = f0 >> 2, cg0 = (f0 & 3) ^ (rA0 & 3);
  int rA1 = f1 >> 2, cg1 = (f1 & 3) ^ (rA1 & 3);
  const ushort_t* gA0 = A + (size_t)(m0 + rA0) * K + cg0 * 8;
  const ushort_t* gA1 = A + (size_t)(m0 + rA1) * K + cg1 * 8;
  const ushort_t* gB0 = W + (size_t)(n0 + rA0) * K + cg0 * 8;
  const ushort_t* gB1 = W + (size_t)(n0 + rA1) * K + cg1 * 8;
  ushort_t* lA0 = &As[f0 * 8];
  ushort_t* lA1 = &As[f1 * 8];
  ushort_t* lB0 = &Bs[f0 * 8];
  ushort_t* lB1 = &Bs[f1 * 8];

  int swz = quad ^ (lr & 3);

  for (int k0 = 0; k0 < K; k0 += 32) {
    __syncthreads();
    gload16(gA0 + k0, lA0);
    gload16(gA1 + k0, lA1);
    gload16(gB0 + k0, lB0);
    gload16(gB1 + k0, lB1);
    __syncthreads();   // drains vmcnt before barrier

    bf16x8 af[4], bff[4];
#pragma unroll
    for (int i = 0; i < 4; ++i) {
      af[i] = *(const bf16x8*)&As[((wm + i * 16 + lr) * 4 + swz) * 8];
      bff[i] = *(const bf16x8*)&Bs[((wn + i * 16 + lr) * 4 + swz) * 8];
    }
#pragma unroll
    for (int i = 0; i < 4; ++i)
#pragma unroll
      for (int j = 0; j < 4; ++j)
        acc[i][j] = __builtin_amdgcn_mfma_f32_16x16x32_bf16(af[i], bff[j],
                                                            acc[i][j], 0, 0, 0);
  }

  float sg = 0.0f;
  if (MODE == 2) sg = 1.0f / (1.0f + expf(-gptr[0]));

#pragma unroll
  for (int j = 0; j < 4; ++j) {
    int n = n0 + wn + j * 16 + lr;
    float bv = bias[n];
#pragma unroll
    for (int i = 0; i < 4; ++i) {
      int mbase = m0 + wm + i * 16 + quad * 4;
#pragma unroll
      for (int r = 0; r < 4; ++r) {
        int m = mbase + r;
        float x = acc[i][j][r] + bv;
        if (MODE == 1) x = 0.5f * x * (1.0f + erff(x * 0.70710678118654752f));
        if (MODE == 2) x = bf2f(EXTRA[(size_t)m * N + n]) + sg * x;
        if (MODE == 3) x = x + bf2f(EXTRA[(size_t)m * N + n]);
        if (OUTBF) ((ushort_t*)Cout)[(size_t)m * N + n] = f2bf(x);
        else       ((float*)Cout)[(size_t)m * N + n] = x;
      }
    }
  }
}

// ---------------------------------------------------------------------------
// Self-attention (bf16 qkv in, bf16 sa out); one block per (batch, head).
// ---------------------------------------------------------------------------
__global__ __launch_bounds__(256) void attn_kernel(
    const ushort_t* __restrict__ qkv, ushort_t* __restrict__ sa) {
  int bh = blockIdx.x;
  int b = bh >> 3;
  int h = bh & 7;
  __shared__ float Ks[KSEL][68];
  __shared__ float Qs[16][68];
  __shared__ float Ss[16][156];
  __shared__ float rinv[16];
  int t = threadIdx.x;
  const ushort_t* base = qkv + (size_t)b * KSEL * 1536;

  for (int e = t; e < KSEL * 8; e += 256) {   // 8 bf16 per step
    int j = e >> 3, g = e & 7;
    const uint4 w = *(const uint4*)(base + (size_t)j * 1536 + 512 + h * 64 + g * 8);
    float* d = &Ks[j][g * 8];
    d[0] = __uint_as_float(w.x << 16); d[1] = __uint_as_float(w.x & 0xffff0000u);
    d[2] = __uint_as_float(w.y << 16); d[3] = __uint_as_float(w.y & 0xffff0000u);
    d[4] = __uint_as_float(w.z << 16); d[5] = __uint_as_float(w.z & 0xffff0000u);
    d[6] = __uint_as_float(w.w << 16); d[7] = __uint_as_float(w.w & 0xffff0000u);
  }
  __syncthreads();

  for (int i0 = 0; i0 < KSEL; i0 += 16) {
    int rows = min(16, KSEL - i0);
    for (int e = t; e < rows * 8; e += 256) {
      int i = e >> 3, g = e & 7;
      const uint4 w = *(const uint4*)(base + (size_t)(i0 + i) * 1536 + h * 64 + g * 8);
      float* d = &Qs[i][g * 8];
      d[0] = __uint_as_float(w.x << 16); d[1] = __uint_as_float(w.x & 0xffff0000u);
      d[2] = __uint_as_float(w.y << 16); d[3] = __uint_as_float(w.y & 0xffff0000u);
      d[4] = __uint_as_float(w.z << 16); d[5] = __uint_as_float(w.z & 0xffff0000u);
      d[6] = __uint_as_float(w.w << 16); d[7] = __uint_as_float(w.w & 0xffff0000u);
    }
    __syncthreads();

    int i = t >> 4, jl = t & 15;
    if (i < rows) {
      for (int j = jl; j < KSEL; j += 16) {
        float acc = 0.0f;
#pragma unroll
        for (int d = 0; d < 64; d += 4) {
          float4 q4 = *(const float4*)&Qs[i][d];
          float4 k4 = *(const float4*)&Ks[j][d];
          acc += q4.x * k4.x + q4.y * k4.y + q4.z * k4.z + q4.w * k4.w;
        }
        Ss[i][j] = acc * 0.125f;
      }
    }
    __syncthreads();

    if (i < rows) {
      float mx = -3.0e38f;
      for (int j = jl; j < KSEL; j += 16) mx = fmaxf(mx, Ss[i][j]);
      for (int o = 8; o > 0; o >>= 1) mx = fmaxf(mx, __shfl_xor(mx, o));
      float sm = 0.0f;
      for (int j = jl; j < KSEL; j += 16) {
        float e = expf(Ss[i][j] - mx);
        Ss[i][j] = e;
        sm += e;
      }
      for (int o = 8; o > 0; o >>= 1) sm += __shfl_xor(sm, o);
      if (jl == 0) rinv[i] = 1.0f / sm;
    }
    __syncthreads();

    {
      int ii = t >> 4, d0 = (t & 15) * 4;
      if (ii < rows) {
        float ax = 0.f, ay = 0.f, az = 0.f, aw = 0.f;
        for (int j = 0; j < KSEL; ++j) {
          float p = Ss[ii][j];
          uint2 w = *(const uint2*)(base + (size_t)j * 1536 + 1024 + h * 64 + d0);
          ax += p * __uint_as_float(w.x << 16);
          ay += p * __uint_as_float(w.x & 0xffff0000u);
          az += p * __uint_as_float(w.y << 16);
          aw += p * __uint_as_float(w.y & 0xffff0000u);
        }
        float r = rinv[ii];
        ushort4 o;
        o.x = f2bf(ax * r); o.y = f2bf(ay * r);
        o.z = f2bf(az * r); o.w = f2bf(aw * r);
        *(ushort4*)&sa[(size_t)(b * KSEL + i0 + ii) * DDIM + h * 64 + d0] = o;
      }
    }
    __syncthreads();
  }
}

// ---------------------------------------------------------------------------
// BatchNorm stats (fp32 in), finalize, apply (fp32 in -> bf16 out + relu)
// ---------------------------------------------------------------------------
__global__ __launch_bounds__(256) void bn_stats_kernel(
    const float* __restrict__ h, float* __restrict__ sum, float* __restrict__ ssq) {
  int blk = blockIdx.x;
  int t = threadIdx.x;
  float a0 = 0.f, a1 = 0.f, q0 = 0.f, q1 = 0.f;
  for (int r = 0; r < 128; ++r) {
    const float* row = h + ((size_t)blk * 128 + r) * 512;
    float v0 = row[t], v1 = row[t + 256];
    a0 += v0; q0 += v0 * v0;
    a1 += v1; q1 += v1 * v1;
  }
  atomicAdd(&sum[t], a0);       atomicAdd(&ssq[t], q0);
  atomicAdd(&sum[t + 256], a1); atomicAdd(&ssq[t + 256], q1);
}

__global__ void bn_finalize_kernel(const float* __restrict__ sum,
                                   const float* __restrict__ ssq,
                                   float* __restrict__ mu, float* __restrict__ istd) {
  int c = blockIdx.x * 256 + threadIdx.x;
  if (c < 512) {
    float m = sum[c] * (1.0f / MTOT);
    float v = ssq[c] * (1.0f / MTOT) - m * m;
    mu[c] = m;
    istd[c] = rsqrtf(v + 1e-5f);
  }
}

__global__ __launch_bounds__(256) void bn_apply_kernel(
    const float* __restrict__ h, const float* __restrict__ mu,
    const float* __restrict__ istd, const float* __restrict__ w,
    const float* __restrict__ b, ushort_t* __restrict__ outb) {
  int i4 = blockIdx.x * 256 + threadIdx.x;
  int c0 = (i4 * 4) & 511;
  float4 v = *(const float4*)&h[(size_t)i4 * 4];
  ushort4 o;
  o.x = f2bf(fmaxf((v.x - mu[c0 + 0]) * istd[c0 + 0] * w[c0 + 0] + b[c0 + 0], 0.f));
  o.y = f2bf(fmaxf((v.y - mu[c0 + 1]) * istd[c0 + 1] * w[c0 + 1] + b[c0 + 1], 0.f));
  o.z = f2bf(fmaxf((v.z - mu[c0 + 2]) * istd[c0 + 2] * w[c0 + 2] + b[c0 + 2], 0.f));
  o.w = f2bf(fmaxf((v.w - mu[c0 + 3]) * istd[c0 + 3] * w[c0 + 3] + b[c0 + 3], 0.f));
  *(ushort4*)&outb[(size_t)i4 * 4] = o;
}

// ---------------------------------------------------------------------------
// Variable-length max pool over first lens[b] ranked tokens (bf16 in, f32 out)
// ---------------------------------------------------------------------------
__global__ __launch_bounds__(256) void pool_kernel(
    const ushort_t* __restrict__ feat, const int* __restrict__ lens,
    float* __restrict__ out) {
  int b = blockIdx.x;
  int t = threadIdx.x;
  int L = lens[b];
  for (int e = t; e < 1024; e += 256) {
    const ushort_t* p = feat + (size_t)b * KSEL * 1024 + e;
    float mx = -3.0e38f;
    for (int i = 0; i < L; ++i) mx = fmaxf(mx, bf2f(p[(size_t)i * 1024]));
    out[(size_t)b * 1024 + e] = mx;
  }
}

// ---------------------------------------------------------------------------
extern "C" void kernel_launch(void* const* d_in, const int* in_sizes, int n_in,
                              void* d_out, int out_size, void* d_ws, size_t ws_size,
                              hipStream_t stream) {
  const float* features = (const float*)d_in[0];
  const int*   text     = (const int*)d_in[1];
  const float* atten    = (const float*)d_in[2];
  const float* ln_q_w   = (const float*)d_in[3];
  const float* ln_q_b   = (const float*)d_in[4];
  const float* sa_in_w  = (const float*)d_in[5];
  const float* sa_in_b  = (const float*)d_in[6];
  const float* sa_out_w = (const float*)d_in[7];
  const float* sa_out_b = (const float*)d_in[8];
  const float* ref_w1   = (const float*)d_in[9];
  const float* ref_b1   = (const float*)d_in[10];
  const float* ref_w2   = (const float*)d_in[11];
  const float* ref_b2   = (const float*)d_in[12];
  const float* gptr     = (const float*)d_in[13];
  const float* lin_w    = (const float*)d_in[14];
  const float* lin_b    = (const float*)d_in[15];
  const float* mlp_w1   = (const float*)d_in[16];
  const float* mlp_b1   = (const float*)d_in[17];
  const float* bn_w     = (const float*)d_in[18];
  const float* bn_b     = (const float*)d_in[19];
  const float* mlp_w2   = (const float*)d_in[20];
  const float* mlp_b2   = (const float*)d_in[21];
  float* out = (float*)d_out;

  char* wsb = (char*)d_ws;
  int*     idxp  = (int*)(wsb + 0);              // 156,672
  int*     lensp = (int*)(wsb + 157696);
  float*   sump  = (float*)(wsb + 158720);
  float*   ssqp  = (float*)(wsb + 160768);
  float*   mup   = (float*)(wsb + 162816);
  float*   istdp = (float*)(wsb + 164864);
  ushort_t* wb   = (ushort_t*)(wsb + 166912);    // 6,815,744 B of bf16 weights
  // bf16 weight element offsets
  const int WQ = 0, WO = 786432, W1 = 1048576, W2 = 1572864,
            WL = 2097152, WM1 = 2621440, WM2 = 2883584, WEND = 3407872;

  ushort_t* tokb = (ushort_t*)(wsb + 7000064);    // [M,512]  40,108,032
  ushort_t* qb   = (ushort_t*)(wsb + 47108096);   // [M,512]  (later SA, H1b)
  ushort_t* qkvb = (ushort_t*)(wsb + 87216128);   // [M,1536] 120,324,096
  ushort_t* s2b  = (ushort_t*)(wsb + 87216128);   // [M,512]  (qkv dead)
  ushort_t* hb   = (ushort_t*)(wsb + 127324160);  // [M,1024] (qkv tail)
  float*    h1f  = (float*)(wsb + 127324160);     // [M,512] f32 (hb dead)
  ushort_t* sab  = qb;                            // [M,512] (qb dead)
  ushort_t* h1b  = qb;                            // [M,512] (sab dead)
  ushort_t* capb = (ushort_t*)(wsb + 207540224);  // [M,1024] 80,216,064
  // arena end: 287,756,288 bytes

  hipMemsetAsync(sump, 0, 4096, stream);          // sum + ssq

  WConvArgs wa;
  wa.src[0] = sa_in_w; wa.src[1] = sa_out_w; wa.src[2] = ref_w1;
  wa.src[3] = ref_w2;  wa.src[4] = lin_w;    wa.src[5] = mlp_w1;
  wa.src[6] = mlp_w2;
  wa.e[0] = WQ; wa.e[1] = WO; wa.e[2] = W1; wa.e[3] = W2;
  wa.e[4] = WL; wa.e[5] = WM1; wa.e[6] = WM2; wa.e[7] = WEND;
  wconv_kernel<<<(WEND / 4 + 255) / 256, 256, 0, stream>>>(wa, wb);

  prep_kernel<<<BATCH, 512, 0, stream>>>(text, atten, idxp, lensp);
  gather_ln_kernel<<<MTOT, 256, 0, stream>>>(features, idxp, ln_q_w, ln_q_b,
                                             tokb, qb);
  // qkv = LN(tok) @ sa_in_w^T + b           [M,1536] bf16
  mfma_gemm<0, 1><<<dim3(12, MTOT / 128), 256, 0, stream>>>(
      qb, wb + WQ, sa_in_b, qkvb, nullptr, nullptr, MTOT, 1536, 512);
  // self-attention -> SA bf16 (into qb region)
  attn_kernel<<<BATCH * 8, 256, 0, stream>>>(qkvb, sab);
  // S2 = SA @ sa_out_w^T + b                [M,512] bf16 (into qkv region)
  mfma_gemm<0, 1><<<dim3(4, MTOT / 128), 256, 0, stream>>>(
      sab, wb + WO, sa_out_b, s2b, nullptr, nullptr, MTOT, 512, 512);
  // H = gelu(S2 @ ref_w1^T + b)             [M,1024] bf16
  mfma_gemm<1, 1><<<dim3(8, MTOT / 128), 256, 0, stream>>>(
      s2b, wb + W1, ref_b1, hb, nullptr, nullptr, MTOT, 1024, 512);
  // tok = tok + sigmoid(g)*(H @ ref_w2^T+b) [M,512] bf16, in-place on tokb
  mfma_gemm<2, 1><<<dim3(4, MTOT / 128), 256, 0, stream>>>(
      hb, wb + W2, ref_b2, tokb, tokb, gptr, MTOT, 512, 1024);
  // cap = tok @ lin_w^T + b                 [M,1024] bf16
  mfma_gemm<0, 1><<<dim3(8, MTOT / 128), 256, 0, stream>>>(
      tokb, wb + WL, lin_b, capb, nullptr, nullptr, MTOT, 1024, 512);
  // h = tok @ mlp_w1^T + b                  [M,512] fp32 (BN stats want f32)
  mfma_gemm<0, 0><<<dim3(4, MTOT / 128), 256, 0, stream>>>(
      tokb, wb + WM1, mlp_b1, h1f, nullptr, nullptr, MTOT, 512, 512);
  // BN train-mode stats + apply + relu -> bf16
  bn_stats_kernel<<<MTOT / 128, 256, 0, stream>>>(h1f, sump, ssqp);
  bn_finalize_kernel<<<2, 256, 0, stream>>>(sump, ssqp, mup, istdp);
  bn_apply_kernel<<<(MTOT * 512 / 4) / 256, 256, 0, stream>>>(h1f, mup, istdp,
                                                              bn_w, bn_b, h1b);
  // feat = relu_bn(h) @ mlp_w2^T + b + cap  [M,1024] bf16, in-place on capb
  mfma_gemm<3, 1><<<dim3(8, MTOT / 128), 256, 0, stream>>>(
      h1b, wb + WM2, mlp_b2, capb, capb, nullptr, MTOT, 1024, 512);
  // masked max pool
  pool_kernel<<<BATCH, 256, 0, stream>>>(capb, lensp, out);
}

// Round 4
// 1207.505 us; speedup vs baseline: 4.1517x; 1.5002x over previous
//
#include <hip/hip_runtime.h>
#include <math.h>

#define KSEL 153
#define NT 512
#define DDIM 512
#define BATCH 256
#define MTOT (BATCH * KSEL)   // 39168

typedef unsigned short ushort_t;
typedef short bf16x8 __attribute__((ext_vector_type(8)));
typedef short bf16x4 __attribute__((ext_vector_type(4)));
typedef float f32x4 __attribute__((ext_vector_type(4)));

__device__ __forceinline__ ushort_t f2bf(float f) {
  unsigned u = __float_as_uint(f);
  u += 0x7fffu + ((u >> 16) & 1u);       // RNE
  return (ushort_t)(u >> 16);
}
__device__ __forceinline__ float bf2f(ushort_t s) {
  return __uint_as_float(((unsigned)s) << 16);
}
__device__ __forceinline__ void gload16(const void* g, void* l) {
  __builtin_amdgcn_global_load_lds(
      (const __attribute__((address_space(1))) unsigned int*)g,
      (__attribute__((address_space(3))) unsigned int*)l, 16, 0, 0);
}

// ---------------------------------------------------------------------------
// Stage 1: per-batch prep — eos, lengths, exact top-k via bitonic sort.
// ---------------------------------------------------------------------------
__global__ __launch_bounds__(512) void prep_kernel(
    const int* __restrict__ text, const float* __restrict__ atten,
    int* __restrict__ idx, int* __restrict__ lens) {
  int b = blockIdx.x;
  int t = threadIdx.x;  // 0..511
  __shared__ int red[512];
  __shared__ int eos_s;
  __shared__ int cnt_s;
  __shared__ unsigned long long keys[512];

  int ti = text[b * NT + t];
  red[t] = ti;
  if (t == 0) { eos_s = 0x7fffffff; cnt_s = 0; }
  __syncthreads();
  for (int s = 256; s > 0; s >>= 1) {
    if (t < s) red[t] = max(red[t], red[t + s]);
    __syncthreads();
  }
  int mxv = red[0];
  if (ti == mxv) atomicMin(&eos_s, t);
  unsigned long long bal = __ballot(ti != 0);
  if ((t & 63) == 0) atomicAdd(&cnt_s, __popcll(bal));
  __syncthreads();
  int eos = eos_s;

  float v;
  if (ti == 0) v = 0.0f;
  else if (t == 0 || t == eos) v = -1.0f;
  else v = atten[((size_t)b * NT + eos) * NT + t];
  unsigned int fb = __float_as_uint(v);
  unsigned int ordv = (v >= 0.0f) ? (fb | 0x80000000u) : ~fb;
  keys[t] = ((unsigned long long)ordv << 32) | (unsigned int)(511 - t);
  __syncthreads();

  for (int k2 = 2; k2 <= 512; k2 <<= 1) {
    for (int j = k2 >> 1; j > 0; j >>= 1) {
      int ixj = t ^ j;
      if (ixj > t) {
        unsigned long long a = keys[t], bb = keys[ixj];
        bool up = ((t & k2) == 0);
        bool sw = up ? (a < bb) : (a > bb);
        if (sw) { keys[t] = bb; keys[ixj] = a; }
      }
      __syncthreads();
    }
  }
  if (t < KSEL) idx[b * KSEL + t] = 511 - (int)(keys[t] & 0xffffffffu);
  if (t == 0) {
    int L = cnt_s - 2;
    L = min(L, KSEL); L = max(L, 1);
    lens[b] = L;
  }
}

// ---------------------------------------------------------------------------
// Stage 2: gather + L2-normalize + LayerNorm; writes tok(bf16) and q(bf16).
// ---------------------------------------------------------------------------
__global__ __launch_bounds__(256) void gather_ln_kernel(
    const float* __restrict__ features, const int* __restrict__ idx,
    const float* __restrict__ lnw, const float* __restrict__ lnb,
    ushort_t* __restrict__ tokb, ushort_t* __restrict__ qb) {
  int m = blockIdx.x;
  int b = m / KSEL;
  int t = threadIdx.x;
  int src = idx[m];
  const float* f = features + ((size_t)b * NT + src) * DDIM;
  float v0 = f[t], v1 = f[t + 256];
  float s1 = v0 + v1, s2 = v0 * v0 + v1 * v1;
  for (int o = 32; o > 0; o >>= 1) {
    s1 += __shfl_xor(s1, o);
    s2 += __shfl_xor(s2, o);
  }
  __shared__ float w1[4], w2[4];
  int wv = t >> 6;
  if ((t & 63) == 0) { w1[wv] = s1; w2[wv] = s2; }
  __syncthreads();
  s1 = w1[0] + w1[1] + w1[2] + w1[3];
  s2 = w2[0] + w2[1] + w2[2] + w2[3];
  float dn = sqrtf(s2) + 1e-6f;
  float t0 = v0 / dn, t1 = v1 / dn;
  float mean = s1 / dn * (1.0f / DDIM);
  float ex2 = s2 / (dn * dn) * (1.0f / DDIM);
  float var = ex2 - mean * mean;
  float is = rsqrtf(var + 1e-5f);
  size_t rowo = (size_t)m * DDIM;
  tokb[rowo + t] = f2bf(t0);
  tokb[rowo + t + 256] = f2bf(t1);
  qb[rowo + t] = f2bf((t0 - mean) * is * lnw[t] + lnb[t]);
  qb[rowo + t + 256] = f2bf((t1 - mean) * is * lnw[t + 256] + lnb[t + 256]);
}

// ---------------------------------------------------------------------------
// Weight fp32 -> bf16 conversion (all 7 matrices, one kernel).
// ---------------------------------------------------------------------------
struct WConvArgs {
  const float* src[7];
  int e[8];   // cumulative element offsets
};
__global__ __launch_bounds__(256) void wconv_kernel(WConvArgs a, ushort_t* dst) {
  int gid = blockIdx.x * 256 + threadIdx.x;
  int el = gid * 4;
  if (el >= a.e[7]) return;
  int r = 0;
#pragma unroll
  for (int i = 1; i < 7; ++i) r += (el >= a.e[i]) ? 1 : 0;
  const float* s = a.src[r] + (el - a.e[r]);
  float4 v = *(const float4*)s;
  ushort4 o;
  o.x = f2bf(v.x); o.y = f2bf(v.y); o.z = f2bf(v.z); o.w = f2bf(v.w);
  *(ushort4*)(dst + el) = o;
}

// ---------------------------------------------------------------------------
// MFMA bf16 GEMM: C[M,N] = epi(A[M,K] @ W[N,K]^T + bias)
// 128x128 tile, BK=32, 256 thr, global_load_lds staging w/ XOR swizzle.
// MODE 0: bias  1: +exact gelu  2: out = bf(EXTRA) + sigmoid(*gptr)*x
// MODE 3: out = x + bf(EXTRA).  OUTBF: write bf16 else fp32.
// ---------------------------------------------------------------------------
template <int MODE, int OUTBF>
__global__ __launch_bounds__(256) void mfma_gemm(
    const ushort_t* __restrict__ A, const ushort_t* __restrict__ W,
    const float* __restrict__ bias, void* __restrict__ Cout,
    const ushort_t* __restrict__ EXTRA, const float* __restrict__ gptr,
    int M, int N, int K) {
  __shared__ ushort_t As[128 * 32];
  __shared__ ushort_t Bs[128 * 32];
  int t = threadIdx.x;
  int lane = t & 63;
  int wv = t >> 6;
  int m0 = blockIdx.y * 128, n0 = blockIdx.x * 128;
  int wm = (wv >> 1) * 64, wn = (wv & 1) * 64;
  int quad = lane >> 4, lr = lane & 15;

  f32x4 acc[4][4];
#pragma unroll
  for (int i = 0; i < 4; ++i)
#pragma unroll
    for (int j = 0; j < 4; ++j) acc[i][j] = (f32x4){0.f, 0.f, 0.f, 0.f};

  int f0 = t, f1 = t + 256;
  int rA0 = f0 >> 2, cg0 = (f0 & 3) ^ (rA0 & 3);
  int rA1 = f1 >> 2, cg1 = (f1 & 3) ^ (rA1 & 3);
  const ushort_t* gA0 = A + (size_t)(m0 + rA0) * K + cg0 * 8;
  const ushort_t* gA1 = A + (size_t)(m0 + rA1) * K + cg1 * 8;
  const ushort_t* gB0 = W + (size_t)(n0 + rA0) * K + cg0 * 8;
  const ushort_t* gB1 = W + (size_t)(n0 + rA1) * K + cg1 * 8;
  ushort_t* lA0 = &As[f0 * 8];
  ushort_t* lA1 = &As[f1 * 8];
  ushort_t* lB0 = &Bs[f0 * 8];
  ushort_t* lB1 = &Bs[f1 * 8];

  int swz = quad ^ (lr & 3);

  for (int k0 = 0; k0 < K; k0 += 32) {
    __syncthreads();
    gload16(gA0 + k0, lA0);
    gload16(gA1 + k0, lA1);
    gload16(gB0 + k0, lB0);
    gload16(gB1 + k0, lB1);
    __syncthreads();

    bf16x8 af[4], bff[4];
#pragma unroll
    for (int i = 0; i < 4; ++i) {
      af[i] = *(const bf16x8*)&As[((wm + i * 16 + lr) * 4 + swz) * 8];
      bff[i] = *(const bf16x8*)&Bs[((wn + i * 16 + lr) * 4 + swz) * 8];
    }
#pragma unroll
    for (int i = 0; i < 4; ++i)
#pragma unroll
      for (int j = 0; j < 4; ++j)
        acc[i][j] = __builtin_amdgcn_mfma_f32_16x16x32_bf16(af[i], bff[j],
                                                            acc[i][j], 0, 0, 0);
  }

  float sg = 0.0f;
  if (MODE == 2) sg = 1.0f / (1.0f + expf(-gptr[0]));

#pragma unroll
  for (int j = 0; j < 4; ++j) {
    int n = n0 + wn + j * 16 + lr;
    float bv = bias[n];
#pragma unroll
    for (int i = 0; i < 4; ++i) {
      int mbase = m0 + wm + i * 16 + quad * 4;
#pragma unroll
      for (int r = 0; r < 4; ++r) {
        int m = mbase + r;
        float x = acc[i][j][r] + bv;
        if (MODE == 1) x = 0.5f * x * (1.0f + erff(x * 0.70710678118654752f));
        if (MODE == 2) x = bf2f(EXTRA[(size_t)m * N + n]) + sg * x;
        if (MODE == 3) x = x + bf2f(EXTRA[(size_t)m * N + n]);
        if (OUTBF) ((ushort_t*)Cout)[(size_t)m * N + n] = f2bf(x);
        else       ((float*)Cout)[(size_t)m * N + n] = x;
      }
    }
  }
}

// ---------------------------------------------------------------------------
// Stage 4: MFMA self-attention. One block per (batch, head), 4 waves.
// K in LDS natural [key][d] (stride 72), V transposed [d][key] (stride 168),
// per-wave P buffer [row][key] (stride 164). Q read direct from global.
// Wave w handles 16-row q-tiles i0 = 16w, 16w+64, ... (10 tiles, 3/3/2/2).
// S kept entirely in registers (10 x f32x4); softmax via 16-lane shuffles.
// LDS total = 23040 + 21504 + 4*5248 = 65536 B.
// ---------------------------------------------------------------------------
#define KST 72    // Kb row stride (bf16 elems): 144B -> 2-way (free)
#define VST 168   // Vt row stride: 336B -> 2-way (free), 16B aligned
#define PST 164   // P row stride: 328B -> conflict-free for 8B reads
__global__ __launch_bounds__(256) void attn_mfma_kernel(
    const ushort_t* __restrict__ qkv, ushort_t* __restrict__ sa) {
  int bh = blockIdx.x;
  int b = bh >> 3, h = bh & 7;
  __shared__ ushort_t Kb[160 * KST];
  __shared__ ushort_t Vt[64 * VST];
  __shared__ ushort_t Pw[4][16 * PST];
  int t = threadIdx.x;
  int lane = t & 63, wv = t >> 6;
  int quad = lane >> 4, lr = lane & 15;
  const ushort_t* base = qkv + (size_t)b * KSEL * 1536 + h * 64;

  // zero Vt pad keys 153..160 (P is 0 there, but 0*garbage-NaN would poison)
  for (int c = t; c < 64 * 8; c += 256) {
    int d = c >> 3, key = 153 + (c & 7);
    Vt[d * VST + key] = 0;
  }
  // stage K [key][d]  (8 bf16 per uint4 -> g in 0..7 covers all 64 dims)
  for (int c = t; c < 153 * 8; c += 256) {
    int key = c >> 3, g = c & 7;
    uint4 w = *(const uint4*)(base + (size_t)key * 1536 + 512 + g * 8);
    *(uint4*)&Kb[key * KST + g * 8] = w;
  }
  // stage V transposed [d][key]
  for (int c = t; c < 153 * 8; c += 256) {
    int key = c >> 3, g = c & 7;
    union { uint4 u; ushort_t s[8]; } w;
    w.u = *(const uint4*)(base + (size_t)key * 1536 + 1024 + g * 8);
#pragma unroll
    for (int j = 0; j < 8; ++j) Vt[(g * 8 + j) * VST + key] = w.s[j];
  }
  __syncthreads();

  ushort_t* P = Pw[wv];

  for (int i0 = wv * 16; i0 < 160; i0 += 64) {
    // Q fragments (A-layout): row = lr (clamped), k = 32*ks + quad*8
    int qrow = min(i0 + lr, KSEL - 1);
    const ushort_t* qg = base + (size_t)qrow * 1536;
    bf16x8 qf0 = *(const bf16x8*)(qg + quad * 8);
    bf16x8 qf1 = *(const bf16x8*)(qg + 32 + quad * 8);

    // S = Q @ K^T * scale   (10 n-tiles of 16 keys, C-layout registers)
    f32x4 s[10];
#pragma unroll
    for (int j0 = 0; j0 < 10; ++j0) {
      const ushort_t* kr = &Kb[(j0 * 16 + lr) * KST + quad * 8];
      bf16x8 kf0 = *(const bf16x8*)kr;
      bf16x8 kf1 = *(const bf16x8*)(kr + 32);
      f32x4 acc = (f32x4){0.f, 0.f, 0.f, 0.f};
      acc = __builtin_amdgcn_mfma_f32_16x16x32_bf16(qf0, kf0, acc, 0, 0, 0);
      acc = __builtin_amdgcn_mfma_f32_16x16x32_bf16(qf1, kf1, acc, 0, 0, 0);
      s[j0] = acc * 0.125f;
    }
    // mask pad keys 153..159 (tile 9, cols lr>=9)
    if (lr >= 9) { s[9][0] = s[9][1] = s[9][2] = s[9][3] = -3.0e38f; }

    // softmax per row (row = quad*4+r lives across the 16 lanes of the quad)
    float rinv[4];
#pragma unroll
    for (int r = 0; r < 4; ++r) {
      float m = s[0][r];
#pragma unroll
      for (int j0 = 1; j0 < 10; ++j0) m = fmaxf(m, s[j0][r]);
      for (int o = 1; o < 16; o <<= 1) m = fmaxf(m, __shfl_xor(m, o));
      float sum = 0.f;
#pragma unroll
      for (int j0 = 0; j0 < 10; ++j0) {
        float e = __expf(s[j0][r] - m);
        s[j0][r] = e;
        sum += e;
      }
      for (int o = 1; o < 16; o <<= 1) sum += __shfl_xor(sum, o);
      rinv[r] = 1.0f / sum;
    }

    // P (bf16, already normalized) -> per-wave LDS in A-layout [row][key]
#pragma unroll
    for (int j0 = 0; j0 < 10; ++j0)
#pragma unroll
      for (int r = 0; r < 4; ++r)
        P[(quad * 4 + r) * PST + j0 * 16 + lr] = f2bf(s[j0][r] * rinv[r]);
    __asm__ volatile("s_waitcnt lgkmcnt(0)" ::: "memory");

    // O = P @ V  (A-frag from P LDS, B-frag from Vt; 5 k-steps of 32 keys)
    f32x4 o[4];
#pragma unroll
    for (int jd = 0; jd < 4; ++jd) o[jd] = (f32x4){0.f, 0.f, 0.f, 0.f};
#pragma unroll
    for (int ks = 0; ks < 5; ++ks) {
      const ushort_t* pr = &P[lr * PST + ks * 32 + quad * 8];
      bf16x4 plo = *(const bf16x4*)pr;
      bf16x4 phi = *(const bf16x4*)(pr + 4);
      bf16x8 pf = {plo[0], plo[1], plo[2], plo[3],
                   phi[0], phi[1], phi[2], phi[3]};
#pragma unroll
      for (int jd = 0; jd < 4; ++jd) {
        bf16x8 vf = *(const bf16x8*)&Vt[(jd * 16 + lr) * VST + ks * 32 + quad * 8];
        o[jd] = __builtin_amdgcn_mfma_f32_16x16x32_bf16(pf, vf, o[jd], 0, 0, 0);
      }
    }

    // store O rows (C-layout: row = quad*4+r, col = jd*16+lr)
#pragma unroll
    for (int r = 0; r < 4; ++r) {
      int q = i0 + quad * 4 + r;
      if (q < KSEL) {
        size_t off = (size_t)(b * KSEL + q) * DDIM + h * 64;
#pragma unroll
        for (int jd = 0; jd < 4; ++jd)
          sa[off + jd * 16 + lr] = f2bf(o[jd][r]);
      }
    }
  }
}

// ---------------------------------------------------------------------------
// BatchNorm stats (fp32 in), finalize, apply (fp32 in -> bf16 out + relu)
// ---------------------------------------------------------------------------
__global__ __launch_bounds__(256) void bn_stats_kernel(
    const float* __restrict__ h, float* __restrict__ sum, float* __restrict__ ssq) {
  int blk = blockIdx.x;
  int t = threadIdx.x;
  float a0 = 0.f, a1 = 0.f, q0 = 0.f, q1 = 0.f;
  for (int r = 0; r < 128; ++r) {
    const float* row = h + ((size_t)blk * 128 + r) * 512;
    float v0 = row[t], v1 = row[t + 256];
    a0 += v0; q0 += v0 * v0;
    a1 += v1; q1 += v1 * v1;
  }
  atomicAdd(&sum[t], a0);       atomicAdd(&ssq[t], q0);
  atomicAdd(&sum[t + 256], a1); atomicAdd(&ssq[t + 256], q1);
}

__global__ void bn_finalize_kernel(const float* __restrict__ sum,
                                   const float* __restrict__ ssq,
                                   float* __restrict__ mu, float* __restrict__ istd) {
  int c = blockIdx.x * 256 + threadIdx.x;
  if (c < 512) {
    float m = sum[c] * (1.0f / MTOT);
    float v = ssq[c] * (1.0f / MTOT) - m * m;
    mu[c] = m;
    istd[c] = rsqrtf(v + 1e-5f);
  }
}

__global__ __launch_bounds__(256) void bn_apply_kernel(
    const float* __restrict__ h, const float* __restrict__ mu,
    const float* __restrict__ istd, const float* __restrict__ w,
    const float* __restrict__ b, ushort_t* __restrict__ outb) {
  int i4 = blockIdx.x * 256 + threadIdx.x;
  int c0 = (i4 * 4) & 511;
  float4 v = *(const float4*)&h[(size_t)i4 * 4];
  ushort4 o;
  o.x = f2bf(fmaxf((v.x - mu[c0 + 0]) * istd[c0 + 0] * w[c0 + 0] + b[c0 + 0], 0.f));
  o.y = f2bf(fmaxf((v.y - mu[c0 + 1]) * istd[c0 + 1] * w[c0 + 1] + b[c0 + 1], 0.f));
  o.z = f2bf(fmaxf((v.z - mu[c0 + 2]) * istd[c0 + 2] * w[c0 + 2] + b[c0 + 2], 0.f));
  o.w = f2bf(fmaxf((v.w - mu[c0 + 3]) * istd[c0 + 3] * w[c0 + 3] + b[c0 + 3], 0.f));
  *(ushort4*)&outb[(size_t)i4 * 4] = o;
}

// ---------------------------------------------------------------------------
// Variable-length max pool over first lens[b] ranked tokens (bf16 in, f32 out)
// ---------------------------------------------------------------------------
__global__ __launch_bounds__(256) void pool_kernel(
    const ushort_t* __restrict__ feat, const int* __restrict__ lens,
    float* __restrict__ out) {
  int b = blockIdx.x;
  int t = threadIdx.x;
  int L = lens[b];
  for (int e = t; e < 1024; e += 256) {
    const ushort_t* p = feat + (size_t)b * KSEL * 1024 + e;
    float mx = -3.0e38f;
    for (int i = 0; i < L; ++i) mx = fmaxf(mx, bf2f(p[(size_t)i * 1024]));
    out[(size_t)b * 1024 + e] = mx;
  }
}

// ---------------------------------------------------------------------------
extern "C" void kernel_launch(void* const* d_in, const int* in_sizes, int n_in,
                              void* d_out, int out_size, void* d_ws, size_t ws_size,
                              hipStream_t stream) {
  const float* features = (const float*)d_in[0];
  const int*   text     = (const int*)d_in[1];
  const float* atten    = (const float*)d_in[2];
  const float* ln_q_w   = (const float*)d_in[3];
  const float* ln_q_b   = (const float*)d_in[4];
  const float* sa_in_w  = (const float*)d_in[5];
  const float* sa_in_b  = (const float*)d_in[6];
  const float* sa_out_w = (const float*)d_in[7];
  const float* sa_out_b = (const float*)d_in[8];
  const float* ref_w1   = (const float*)d_in[9];
  const float* ref_b1   = (const float*)d_in[10];
  const float* ref_w2   = (const float*)d_in[11];
  const float* ref_b2   = (const float*)d_in[12];
  const float* gptr     = (const float*)d_in[13];
  const float* lin_w    = (const float*)d_in[14];
  const float* lin_b    = (const float*)d_in[15];
  const float* mlp_w1   = (const float*)d_in[16];
  const float* mlp_b1   = (const float*)d_in[17];
  const float* bn_w     = (const float*)d_in[18];
  const float* bn_b     = (const float*)d_in[19];
  const float* mlp_w2   = (const float*)d_in[20];
  const float* mlp_b2   = (const float*)d_in[21];
  float* out = (float*)d_out;

  char* wsb = (char*)d_ws;
  int*     idxp  = (int*)(wsb + 0);
  int*     lensp = (int*)(wsb + 157696);
  float*   sump  = (float*)(wsb + 158720);
  float*   ssqp  = (float*)(wsb + 160768);
  float*   mup   = (float*)(wsb + 162816);
  float*   istdp = (float*)(wsb + 164864);
  ushort_t* wb   = (ushort_t*)(wsb + 166912);
  const int WQ = 0, WO = 786432, W1 = 1048576, W2 = 1572864,
            WL = 2097152, WM1 = 2621440, WM2 = 2883584, WEND = 3407872;

  ushort_t* tokb = (ushort_t*)(wsb + 7000064);    // [M,512]
  ushort_t* qb   = (ushort_t*)(wsb + 47108096);   // [M,512]
  ushort_t* qkvb = (ushort_t*)(wsb + 87216128);   // [M,1536]
  ushort_t* s2b  = (ushort_t*)(wsb + 87216128);   // [M,512]
  ushort_t* hb   = (ushort_t*)(wsb + 127324160);  // [M,1024]
  float*    h1f  = (float*)(wsb + 127324160);     // [M,512] f32
  ushort_t* sab  = qb;
  ushort_t* h1b  = qb;
  ushort_t* capb = (ushort_t*)(wsb + 207540224);  // [M,1024]

  hipMemsetAsync(sump, 0, 4096, stream);

  WConvArgs wa;
  wa.src[0] = sa_in_w; wa.src[1] = sa_out_w; wa.src[2] = ref_w1;
  wa.src[3] = ref_w2;  wa.src[4] = lin_w;    wa.src[5] = mlp_w1;
  wa.src[6] = mlp_w2;
  wa.e[0] = WQ; wa.e[1] = WO; wa.e[2] = W1; wa.e[3] = W2;
  wa.e[4] = WL; wa.e[5] = WM1; wa.e[6] = WM2; wa.e[7] = WEND;
  wconv_kernel<<<(WEND / 4 + 255) / 256, 256, 0, stream>>>(wa, wb);

  prep_kernel<<<BATCH, 512, 0, stream>>>(text, atten, idxp, lensp);
  gather_ln_kernel<<<MTOT, 256, 0, stream>>>(features, idxp, ln_q_w, ln_q_b,
                                             tokb, qb);
  mfma_gemm<0, 1><<<dim3(12, MTOT / 128), 256, 0, stream>>>(
      qb, wb + WQ, sa_in_b, qkvb, nullptr, nullptr, MTOT, 1536, 512);
  attn_mfma_kernel<<<BATCH * 8, 256, 0, stream>>>(qkvb, sab);
  mfma_gemm<0, 1><<<dim3(4, MTOT / 128), 256, 0, stream>>>(
      sab, wb + WO, sa_out_b, s2b, nullptr, nullptr, MTOT, 512, 512);
  mfma_gemm<1, 1><<<dim3(8, MTOT / 128), 256, 0, stream>>>(
      s2b, wb + W1, ref_b1, hb, nullptr, nullptr, MTOT, 1024, 512);
  mfma_gemm<2, 1><<<dim3(4, MTOT / 128), 256, 0, stream>>>(
      hb, wb + W2, ref_b2, tokb, tokb, gptr, MTOT, 512, 1024);
  mfma_gemm<0, 1><<<dim3(8, MTOT / 128), 256, 0, stream>>>(
      tokb, wb + WL, lin_b, capb, nullptr, nullptr, MTOT, 1024, 512);
  mfma_gemm<0, 0><<<dim3(4, MTOT / 128), 256, 0, stream>>>(
      tokb, wb + WM1, mlp_b1, h1f, nullptr, nullptr, MTOT, 512, 512);
  bn_stats_kernel<<<MTOT / 128, 256, 0, stream>>>(h1f, sump, ssqp);
  bn_finalize_kernel<<<2, 256, 0, stream>>>(sump, ssqp, mup, istdp);
  bn_apply_kernel<<<(MTOT * 512 / 4) / 256, 256, 0, stream>>>(h1f, mup, istdp,
                                                              bn_w, bn_b, h1b);
  mfma_gemm<3, 1><<<dim3(8, MTOT / 128), 256, 0, stream>>>(
      h1b, wb + WM2, mlp_b2, capb, capb, nullptr, MTOT, 1024, 512);
  pool_kernel<<<BATCH, 256, 0, stream>>>(capb, lensp, out);
}